// Round 13
// baseline (152.939 us; speedup 1.0000x reference)
//
#include <hip/hip_runtime.h>
#include <hip/hip_bf16.h>
#include <math.h>

// CausalFullAttention: out[b,l,h,d] = softmax_s( 0.125*(q.k + bias[l,s]), s<=l ) @ V
// B=4 L=S=2048 H=8 E=D=64, fp32 in/out, bf16 MFMA compute.
// R12: uniform-duration blocks via causal pairing. 256-thread (4-wave) blocks process
//      two 64-row q-chunks sequentially (q-tiles 16+pr and 15-pr) -> every block runs
//      exactly 33 tile-steps; 512 blocks = 2 independent blocks/CU for the whole
//      kernel (no drain/tail, decoupled barriers). Per-wave compute = R10's verified
//      16x16 swapped-QK^T in-register softmax, defer-max, bpermute P re-frag.

typedef __bf16 bf16x8 __attribute__((ext_vector_type(8)));
typedef __bf16 bf16x4 __attribute__((ext_vector_type(4)));
typedef __bf16 bf16x2 __attribute__((ext_vector_type(2)));
typedef float  f32x4  __attribute__((ext_vector_type(4)));
typedef unsigned int u32;
typedef u32 u32x4 __attribute__((ext_vector_type(4)));

#define NB 4
#define NL 2048
#define NS 2048
#define NH 8
#define NE 64
#define ND 64

__device__ __forceinline__ int swz(int d) { return ((d ^ (d >> 3)) & 7) << 3; }

__device__ __forceinline__ u32 cvtpk(float lo, float hi) {
    u32 r;
    asm("v_cvt_pk_bf16_f32 %0, %1, %2" : "=v"(r) : "v"(lo), "v"(hi));
    return r;
}
__device__ __forceinline__ float bpermf(int srclane, float v) {
    return __uint_as_float((u32)__builtin_amdgcn_ds_bpermute(srclane << 2, (int)__float_as_uint(v)));
}
__device__ __forceinline__ u32 bpermu(int srclane, u32 v) {
    return (u32)__builtin_amdgcn_ds_bpermute(srclane << 2, (int)v);
}

__device__ __forceinline__ bf16x8 cvt8s(f32x4 a, f32x4 b, float sc) {
    bf16x8 r;
    r[0]=(__bf16)(a[0]*sc); r[1]=(__bf16)(a[1]*sc); r[2]=(__bf16)(a[2]*sc); r[3]=(__bf16)(a[3]*sc);
    r[4]=(__bf16)(b[0]*sc); r[5]=(__bf16)(b[1]*sc); r[6]=(__bf16)(b[2]*sc); r[7]=(__bf16)(b[3]*sc);
    return r;
}
__device__ __forceinline__ bf16x8 cvt8(f32x4 a, f32x4 b) {
    bf16x8 r;
    r[0]=(__bf16)a[0]; r[1]=(__bf16)a[1]; r[2]=(__bf16)a[2]; r[3]=(__bf16)a[3];
    r[4]=(__bf16)b[0]; r[5]=(__bf16)b[1]; r[6]=(__bf16)b[2]; r[7]=(__bf16)b[3];
    return r;
}

__global__ __launch_bounds__(256)
void fa_fwd(const float* __restrict__ Q, const float* __restrict__ K,
            const float* __restrict__ V, const float* __restrict__ Bias,
            float* __restrict__ Out)
{
    __shared__ __bf16 Klds[2][64][72];   // K tile [kv][e], +8 pad
    __shared__ __bf16 Vlds[2][64][64];   // V^T tile [d][kv], XOR slot swizzle

    const int tid  = threadIdx.x;
    const int w    = tid >> 6, lane = tid & 63;
    const int g    = lane >> 4, li = lane & 15;

    // 512 blocks: bh = id>>4, pair index pr = id&15.
    // Chunk A: q-tile 16+pr (17..32 kv tiles); chunk B: q-tile 15-pr (16..1).
    // Every block: exactly 33 tile-steps -> uniform duration.
    const int id  = blockIdx.x;
    const int bh  = id >> 4, pr = id & 15;
    const int b   = bh >> 3, h = bh & 7;
    const int qtA = 16 + pr, qtB = 15 - pr;

    const float SC = 0.125f * 1.44269504088896340736f;  // scale * log2(e)

    // chunk-invariant staging indices (256 threads, KV tile 64)
    const int skv = tid >> 2,        se0 = (tid & 3) << 4;   // K: row, 16-float chunk
    const int vkv = (tid >> 4) << 2, vd0 = (tid & 15) << 2;  // V: 4kv x 4d sub-block

    const float* kp0 = K + (((size_t)(b * NS + skv)) * NH + h) * NE + se0;
    const float* vp0 = V + (((size_t)(b * NS + vkv)) * NH + h) * ND + vd0;

    f32x4 ka0, ka1, ka2, ka3, va0, va1, va2, va3;   // stage regs
    f32x4 bc[4], bn[4];                             // bias regs

    auto issue_kv = [&](int T) {
        const float* kp = kp0 + (size_t)(T << 6) * (NH * NE);
        ka0 = ((const f32x4*)kp)[0]; ka1 = ((const f32x4*)kp)[1];
        ka2 = ((const f32x4*)kp)[2]; ka3 = ((const f32x4*)kp)[3];
        const float* vp = vp0 + (size_t)(T << 6) * (NH * ND);
        va0 = *(const f32x4*)(vp);
        va1 = *(const f32x4*)(vp + NH * ND);
        va2 = *(const f32x4*)(vp + 2 * NH * ND);
        va3 = *(const f32x4*)(vp + 3 * NH * ND);
    };
    auto write_lds = [&](int buf) {
        *(bf16x8*)&Klds[buf][skv][se0]     = cvt8(ka0, ka1);
        *(bf16x8*)&Klds[buf][skv][se0 + 8] = cvt8(ka2, ka3);
        bf16x4 cc;
        cc[0]=(__bf16)va0[0]; cc[1]=(__bf16)va1[0]; cc[2]=(__bf16)va2[0]; cc[3]=(__bf16)va3[0];
        *(bf16x4*)&Vlds[buf][vd0 + 0][vkv ^ swz(vd0 + 0)] = cc;
        cc[0]=(__bf16)va0[1]; cc[1]=(__bf16)va1[1]; cc[2]=(__bf16)va2[1]; cc[3]=(__bf16)va3[1];
        *(bf16x4*)&Vlds[buf][vd0 + 1][vkv ^ swz(vd0 + 1)] = cc;
        cc[0]=(__bf16)va0[2]; cc[1]=(__bf16)va1[2]; cc[2]=(__bf16)va2[2]; cc[3]=(__bf16)va3[2];
        *(bf16x4*)&Vlds[buf][vd0 + 2][vkv ^ swz(vd0 + 2)] = cc;
        cc[0]=(__bf16)va0[3]; cc[1]=(__bf16)va1[3]; cc[2]=(__bf16)va2[3]; cc[3]=(__bf16)va3[3];
        *(bf16x4*)&Vlds[buf][vd0 + 3][vkv ^ swz(vd0 + 3)] = cc;
    };

    #pragma unroll 1
    for (int ch = 0; ch < 2; ++ch) {
        const int qt = ch ? qtB : qtA;
        const int qb = qt << 6;
        const int qw = qb + (w << 4);       // this wave's first q row
        const int ntiles = qt + 1;

        // Q fragments (B operand of swapped QK^T), pre-scaled
        bf16x8 qa[2];
        {
            const float* qp = Q + (((size_t)(b * NL + qw + li)) * NH + h) * NE;
            #pragma unroll
            for (int eh = 0; eh < 2; ++eh) {
                const int e0 = eh * 32 + g * 8;
                f32x4 f0 = *(const f32x4*)(qp + e0);
                f32x4 f1 = *(const f32x4*)(qp + e0 + 4);
                qa[eh] = cvt8s(f0, f1, SC);
            }
        }

        f32x4 o[4] = {};                    // O: row q = g*4+j, col d = dt*16+li
        float m_run = -INFINITY, l_run = 0.0f;   // per-lane, q-row = qw + li

        const float* bp0 = Bias + (size_t)(qw + li) * NS + g * 4;

        // ---- prologue: stage tile 0 (sync first: LDS reused across chunks) ----
        issue_kv(0);
        #pragma unroll
        for (int c = 0; c < 4; ++c) bc[c] = *(const f32x4*)(bp0 + c * 16);
        __syncthreads();
        write_lds(0);
        __syncthreads();

        for (int t = 0; t < ntiles; ++t) {
            const int cur = t & 1;
            const bool more = (t + 1 < ntiles);

            // phase A: issue next tile's global loads
            if (more) {
                const int kvn = (t + 1) << 6;
                issue_kv(t + 1);
                #pragma unroll
                for (int c = 0; c < 4; ++c) bn[c] = *(const f32x4*)(bp0 + kvn + c * 16);
            }

            // phase B: compute tile t (wave-uniform causal skip)
            const int kv0 = t << 6;
            if (kv0 <= qw + 15) {
                f32x4 s[4];
                #pragma unroll
                for (int c = 0; c < 4; ++c) {
                    f32x4 acc = {};
                    #pragma unroll
                    for (int eh = 0; eh < 2; ++eh) {
                        bf16x8 kb = *(const bf16x8*)&Klds[cur][c * 16 + li][eh * 32 + g * 8];
                        acc = __builtin_amdgcn_mfma_f32_16x16x32_bf16(kb, qa[eh], acc, 0, 0, 0);
                    }
                    s[c] = acc;
                }
                const int lg = qw + li;
                if (kv0 + 63 > qw) {
                    #pragma unroll
                    for (int c = 0; c < 4; ++c)
                        #pragma unroll
                        for (int r = 0; r < 4; ++r) {
                            const int sg = kv0 + c * 16 + g * 4 + r;
                            s[c][r] = (sg <= lg) ? fmaf(bc[c][r], SC, s[c][r]) : -INFINITY;
                        }
                } else {
                    #pragma unroll
                    for (int c = 0; c < 4; ++c)
                        #pragma unroll
                        for (int r = 0; r < 4; ++r)
                            s[c][r] = fmaf(bc[c][r], SC, s[c][r]);
                }
                float pm = fmaxf(
                    fmaxf(fmaxf(fmaxf(s[0][0],s[0][1]),fmaxf(s[0][2],s[0][3])),
                          fmaxf(fmaxf(s[1][0],s[1][1]),fmaxf(s[1][2],s[1][3]))),
                    fmaxf(fmaxf(fmaxf(s[2][0],s[2][1]),fmaxf(s[2][2],s[2][3])),
                          fmaxf(fmaxf(s[3][0],s[3][1]),fmaxf(s[3][2],s[3][3]))));
                pm = fmaxf(pm, __shfl_xor(pm, 16, 64));
                pm = fmaxf(pm, __shfl_xor(pm, 32, 64));
                if (!__all(pm <= m_run + 8.0f)) {     // defer-max (T13)
                    const float mn = fmaxf(m_run, pm);
                    const float corr = exp2f(m_run - mn);
                    m_run = mn; l_run *= corr;
                    #pragma unroll
                    for (int j = 0; j < 4; ++j) {
                        const float cj = bpermf(g * 20 + j, corr);
                        o[0][j] *= cj; o[1][j] *= cj; o[2][j] *= cj; o[3][j] *= cj;
                    }
                }
                #pragma unroll
                for (int c = 0; c < 4; ++c)
                    #pragma unroll
                    for (int r = 0; r < 4; ++r)
                        s[c][r] = exp2f(s[c][r] - m_run);
                float rs = ((s[0][0]+s[0][1])+(s[0][2]+s[0][3]))
                         + ((s[1][0]+s[1][1])+(s[1][2]+s[1][3]))
                         + ((s[2][0]+s[2][1])+(s[2][2]+s[2][3]))
                         + ((s[3][0]+s[3][1])+(s[3][2]+s[3][3]));
                rs += __shfl_xor(rs, 16, 64);
                rs += __shfl_xor(rs, 32, 64);
                l_run += rs;
                // P -> bf16 + re-fragmentation into PV A-frags via bpermute
                const u32 w00 = cvtpk(s[0][0], s[0][1]), w01 = cvtpk(s[0][2], s[0][3]);
                const u32 w10 = cvtpk(s[1][0], s[1][1]), w11 = cvtpk(s[1][2], s[1][3]);
                const u32 w20 = cvtpk(s[2][0], s[2][1]), w21 = cvtpk(s[2][2], s[2][3]);
                const u32 w30 = cvtpk(s[3][0], s[3][1]), w31 = cvtpk(s[3][2], s[3][3]);
                const int slA = (((2 * g) & 3) << 4) | li;
                const int slB = (((2 * g + 1) & 3) << 4) | li;
                const bool hi = (g >= 2);
                u32x4 pw0, pw1;
                {
                    const u32 tA0a = bpermu(slA, w00), tA0b = bpermu(slA, w10);
                    const u32 tA1a = bpermu(slA, w01), tA1b = bpermu(slA, w11);
                    const u32 tB0a = bpermu(slB, w00), tB0b = bpermu(slB, w10);
                    const u32 tB1a = bpermu(slB, w01), tB1b = bpermu(slB, w11);
                    pw0[0] = hi ? tA0b : tA0a;
                    pw0[1] = hi ? tA1b : tA1a;
                    pw0[2] = hi ? tB0b : tB0a;
                    pw0[3] = hi ? tB1b : tB1a;
                    const u32 uA0a = bpermu(slA, w20), uA0b = bpermu(slA, w30);
                    const u32 uA1a = bpermu(slA, w21), uA1b = bpermu(slA, w31);
                    const u32 uB0a = bpermu(slB, w20), uB0b = bpermu(slB, w30);
                    const u32 uB1a = bpermu(slB, w21), uB1b = bpermu(slB, w31);
                    pw1[0] = hi ? uA0b : uA0a;
                    pw1[1] = hi ? uA1b : uA1a;
                    pw1[2] = hi ? uB0b : uB0a;
                    pw1[3] = hi ? uB1b : uB1a;
                }
                const bf16x8 pa0 = __builtin_bit_cast(bf16x8, pw0);
                const bf16x8 pa1 = __builtin_bit_cast(bf16x8, pw1);
                #pragma unroll
                for (int dt = 0; dt < 4; ++dt) {
                    const int d = dt * 16 + li;
                    bf16x8 v0 = *(const bf16x8*)&Vlds[cur][d][(g * 8) ^ swz(d)];
                    bf16x8 v1 = *(const bf16x8*)&Vlds[cur][d][(32 + g * 8) ^ swz(d)];
                    o[dt] = __builtin_amdgcn_mfma_f32_16x16x32_bf16(pa0, v0, o[dt], 0, 0, 0);
                    o[dt] = __builtin_amdgcn_mfma_f32_16x16x32_bf16(pa1, v1, o[dt], 0, 0, 0);
                }
            }

            // phase C/D: write next tile into the other buffer
            if (more) {
                __syncthreads();
                write_lds(cur ^ 1);
                __syncthreads();
                #pragma unroll
                for (int c = 0; c < 4; ++c) bc[c] = bn[c];
            }
        }

        // ---- chunk epilogue: transport l to O layout, normalize, store ----
        #pragma unroll
        for (int j = 0; j < 4; ++j) {
            const float lj = bpermf(g * 20 + j, l_run);
            const float inv = 1.0f / lj;
            const int lgq = qw + g * 4 + j;
            float* op = Out + (((size_t)(b * NL + lgq)) * NH + h) * ND + li;
            op[0]  = o[0][j] * inv;
            op[16] = o[1][j] * inv;
            op[32] = o[2][j] * inv;
            op[48] = o[3][j] * inv;
        }
    }
}

extern "C" void kernel_launch(void* const* d_in, const int* in_sizes, int n_in,
                              void* d_out, int out_size, void* d_ws, size_t ws_size,
                              hipStream_t stream)
{
    const float* Q    = (const float*)d_in[0];
    const float* K    = (const float*)d_in[1];
    const float* V    = (const float*)d_in[2];
    const float* Bias = (const float*)d_in[3];
    // d_in[4] (attn_mask) is the static triu(k=1) causal mask - handled analytically.
    float* Out = (float*)d_out;
    dim3 grid(512);                  // 32 bh x 16 uniform-duration pair-blocks
    dim3 block(256);
    fa_fwd<<<grid, block, 0, stream>>>(Q, K, V, Bias, Out);
}